// Round 11
// baseline (486.756 us; speedup 1.0000x reference)
//
#include <hip/hip_runtime.h>
#include <hip/hip_bf16.h>

#define D       128
#define NNODES  50000
#define NEDGES  600000
#define TE      64           // edges per block (9375 blocks)
#define TN      64           // nodes per block
#define BLK     256
#define LN_EPS  1e-5f

typedef float  fx4    __attribute__((ext_vector_type(4)));
typedef float  f32x4  __attribute__((ext_vector_type(4)));
typedef __bf16 bf16x4 __attribute__((ext_vector_type(4)));
typedef __bf16 bf16x8 __attribute__((ext_vector_type(8)));

// ---- d_ws layout ----
// Fragment-major weights (bf16): frag[kstep][nf][lane(64)][8], 512 bf16/frag.
#define EW1F_OFF 0                         // K=384: 12 ksteps * 8 nf
#define EW2F_OFF (128 * 384)
#define NW1F_OFF (EW2F_OFF + 128 * 128)
#define NW2F_OFF (NW1F_OFF + 128 * 256)
#define WS_ELEMS (NW2F_OFF + 128 * 128)    // 114688 bf16
#define W_BYTES  (WS_ELEMS * 2)
// bf16 aggregation buffer + bf16 x copy
#define AGGB_OFF ((size_t)W_BYTES)
#define XB_OFF   (AGGB_OFF + (size_t)NNODES * D * 2)
#define WS_NEED  (XB_OFF   + (size_t)NNODES * D * 2)   // ~26 MB

__device__ __forceinline__ float silu_f(float z) {
    return z * (1.0f / (1.0f + __expf(-z)));
}

// ---------------------------------------------------------------------------
// Weight prep: f32 [K][128] -> bf16 fragment-major frag[ks][nf][lane][8]
// ---------------------------------------------------------------------------
__global__ __launch_bounds__(256) void prep_weights(
    const float* __restrict__ eW1, const float* __restrict__ eW2,
    const float* __restrict__ nW1, const float* __restrict__ nW2,
    __bf16* __restrict__ ws)
{
    int idx = blockIdx.x * 256 + threadIdx.x;
    if (idx >= WS_ELEMS) return;
    const float* src;
    int local;
    if (idx < EW2F_OFF)      { src = eW1; local = idx; }
    else if (idx < NW1F_OFF) { src = eW2; local = idx - EW2F_OFF; }
    else if (idx < NW2F_OFF) { src = nW1; local = idx - NW1F_OFF; }
    else                     { src = nW2; local = idx - NW2F_OFF; }
    const int f   = local >> 9;
    const int rem = local & 511;
    const int l   = rem >> 3;
    const int j   = rem & 7;
    const int ks  = f >> 3;
    const int nf  = f & 7;
    const int n   = (nf << 4) + (l & 15);
    const int k   = (ks << 5) + ((l >> 4) << 3) + j;
    ws[idx] = (__bf16)src[(size_t)k * D + n];
}

// ---------------------------------------------------------------------------
// x -> bf16 copy (halves gather bytes in the edge kernel)
// ---------------------------------------------------------------------------
__global__ __launch_bounds__(256) void prep_x(
    const float* __restrict__ x, __bf16* __restrict__ xB)
{
    int idx = blockIdx.x * 256 + threadIdx.x;   // fx4 units
    if (idx >= NNODES * D / 4) return;
    fx4 v = ((const fx4*)x)[idx];
    bf16x4 h;
    #pragma unroll
    for (int j = 0; j < 4; ++j) h[j] = (__bf16)v[j];
    ((bf16x4*)xB)[idx] = h;
}

// ---------------------------------------------------------------------------
// Edge kernel — BARRIER-FREE wave-private pipeline. 64 edges/block, 4 waves,
// 16 rows each; every LDS row is touched by exactly one wave, so no
// __syncthreads anywhere (in-order same-wave LDS ordering is sufficient).
// PRE=true : xB bf16 staging + packed-bf16 atomics into aggB.
// PRE=false: fp32 x staging + f32 atomics into aggF.
// ---------------------------------------------------------------------------
template<bool PRE>
__global__ __launch_bounds__(BLK, 4) void edge_kernel(
    const float* __restrict__ x,
    const __bf16* __restrict__ xB,
    const float* __restrict__ edge_attr,
    const int*   __restrict__ edge_index,
    const __bf16* __restrict__ W1f,
    const float* __restrict__ b1,
    const __bf16* __restrict__ W2f,
    const float* __restrict__ b2,
    const float* __restrict__ lng, const float* __restrict__ lnb,
    float* __restrict__ edges_out,
    float* __restrict__ aggF,
    __hip_bfloat162* __restrict__ aggB)
{
    __shared__ __bf16 in_t[TE][264];   // 256 used; h1 aliases cols 0..127 later
    __shared__ int    src_s[TE], dst_s[TE];

    const int tid = threadIdx.x;
    const int e0g = blockIdx.x * TE;

    const int lane  = tid & 63;
    const int wid   = tid >> 6;
    const int wrow0 = wid << 4;        // wave's 16 rows
    const int c16   = lane & 15;
    const int kq    = lane >> 4;
    const int ks8   = kq << 3;
    const int lo8   = lane << 3;       // fragment lane offset (bf16 elems)

    // ---- wave-private id load (rows wrow0..wrow0+15; no barrier) ----
    if (lane < 16) {
        src_s[wrow0 + lane] = edge_index[e0g + wrow0 + lane];          // src (j)
        dst_s[wrow0 + lane] = edge_index[NEDGES + e0g + wrow0 + lane]; // dst (i)
    }

    // ---- edge_attr A-fragments straight from global (block-contiguous) ----
    bf16x8 aE[4];
    {
        const float* ep = edge_attr + (size_t)(e0g + wrow0 + c16) * D + ks8;
        #pragma unroll
        for (int ks2 = 0; ks2 < 4; ++ks2) {
            fx4 v0 = *(const fx4*)(ep + (ks2 << 5));
            fx4 v1 = *(const fx4*)(ep + (ks2 << 5) + 4);
            bf16x8 a;
            #pragma unroll
            for (int j = 0; j < 4; ++j) { a[j] = (__bf16)v0[j]; a[j + 4] = (__bf16)v1[j]; }
            aE[ks2] = a;
        }
    }

    // ---- stage x[dst] | x[src] into this wave's 16 LDS rows ----
    if constexpr (PRE) {
        // bf16 source: 4 rows/pass (16 lanes x 16B = 256B per row), 4 passes/segment
        #pragma unroll
        for (int p = 0; p < 4; ++p) {
            const int row = wrow0 + (p << 2) + (lane >> 4);
            const int c8  = (lane & 15) << 3;
            bf16x8 v = *(const bf16x8*)&xB[(size_t)dst_s[row] * D + c8];
            *(bf16x8*)&in_t[row][c8] = v;
        }
        #pragma unroll
        for (int p = 0; p < 4; ++p) {
            const int row = wrow0 + (p << 2) + (lane >> 4);
            const int c8  = (lane & 15) << 3;
            bf16x8 v = *(const bf16x8*)&xB[(size_t)src_s[row] * D + c8];
            *(bf16x8*)&in_t[row][128 + c8] = v;
        }
    } else {
        // fp32 source: 2 rows/pass (32 lanes x 16B = 512B per row), 8 passes/segment
        #pragma unroll
        for (int p = 0; p < 8; ++p) {
            const int row = wrow0 + (p << 1) + (lane >> 5);
            const int c4  = (lane & 31) << 2;
            fx4 v = *(const fx4*)&x[(size_t)dst_s[row] * D + c4];
            bf16x4 h;
            #pragma unroll
            for (int j = 0; j < 4; ++j) h[j] = (__bf16)v[j];
            *(bf16x4*)&in_t[row][c4] = h;
        }
        #pragma unroll
        for (int p = 0; p < 8; ++p) {
            const int row = wrow0 + (p << 1) + (lane >> 5);
            const int c4  = (lane & 31) << 2;
            fx4 v = *(const fx4*)&x[(size_t)src_s[row] * D + c4];
            bf16x4 h;
            #pragma unroll
            for (int j = 0; j < 4; ++j) h[j] = (__bf16)v[j];
            *(bf16x4*)&in_t[row][128 + c4] = h;
        }
    }
    // no barrier: this wave reads only its own rows below

    // ---- GEMM1: [16,384] @ [384,128] per wave ----
    f32x4 acc[8];
    #pragma unroll
    for (int nf = 0; nf < 8; ++nf) acc[nf] = (f32x4){0.f, 0.f, 0.f, 0.f};

    #pragma unroll
    for (int ks = 0; ks < 12; ++ks) {
        bf16x8 a = (ks < 8) ? *(const bf16x8*)&in_t[wrow0 + c16][(ks << 5) + ks8]
                            : aE[ks - 8];
        const __bf16* wp = W1f + ((size_t)(ks << 3) << 9) + lo8;
        #pragma unroll
        for (int nf = 0; nf < 8; ++nf) {
            bf16x8 b = *(const bf16x8*)(wp + (nf << 9));
            acc[nf] = __builtin_amdgcn_mfma_f32_16x16x32_bf16(a, b, acc[nf], 0, 0, 0);
        }
    }

    // SiLU + bias -> h1 aliased into in_t cols 0..127 (wave-private rows)
    #pragma unroll
    for (int nf = 0; nf < 8; ++nf) {
        const float bb = b1[nf * 16 + c16];
        #pragma unroll
        for (int r = 0; r < 4; ++r) {
            float h = silu_f(acc[nf][r] + bb);
            in_t[wrow0 + kq * 4 + r][nf * 16 + c16] = (__bf16)h;
        }
    }

    // ---- GEMM2: [16,128] @ [128,128] per wave ----
    f32x4 acc2[8];
    #pragma unroll
    for (int nf = 0; nf < 8; ++nf) acc2[nf] = (f32x4){0.f, 0.f, 0.f, 0.f};

    #pragma unroll
    for (int ks = 0; ks < 4; ++ks) {
        bf16x8 a = *(const bf16x8*)&in_t[wrow0 + c16][(ks << 5) + ks8];
        const __bf16* wp = W2f + ((size_t)(ks << 3) << 9) + lo8;
        #pragma unroll
        for (int nf = 0; nf < 8; ++nf) {
            bf16x8 b = *(const bf16x8*)(wp + (nf << 9));
            acc2[nf] = __builtin_amdgcn_mfma_f32_16x16x32_bf16(a, b, acc2[nf], 0, 0, 0);
        }
    }

    // ---- bias + LayerNorm + store + scatter-add ----
    float b2v[8], gv[8], bvv[8];
    #pragma unroll
    for (int nf = 0; nf < 8; ++nf) {
        b2v[nf] = b2[nf * 16 + c16];
        gv[nf]  = lng[nf * 16 + c16];
        bvv[nf] = lnb[nf * 16 + c16];
    }

    float s[4] = {0.f, 0.f, 0.f, 0.f}, q[4] = {0.f, 0.f, 0.f, 0.f};
    #pragma unroll
    for (int nf = 0; nf < 8; ++nf)
        #pragma unroll
        for (int r = 0; r < 4; ++r) {
            float zz = acc2[nf][r] + b2v[nf];
            acc2[nf][r] = zz;
            s[r] += zz;
            q[r] += zz * zz;
        }
    #pragma unroll
    for (int m = 1; m <= 8; m <<= 1)
        #pragma unroll
        for (int r = 0; r < 4; ++r) {
            s[r] += __shfl_xor(s[r], m, 64);
            q[r] += __shfl_xor(q[r], m, 64);
        }

    #pragma unroll
    for (int r = 0; r < 4; ++r) {
        const float mu   = s[r] * (1.0f / 128.0f);
        const float var  = q[r] * (1.0f / 128.0f) - mu * mu;
        const float rstd = rsqrtf(var + LN_EPS);
        const int row = wrow0 + kq * 4 + r;
        const size_t erow = (size_t)(e0g + row) * D;
        const int dn = dst_s[row];
        #pragma unroll
        for (int nf = 0; nf < 8; ++nf) {
            const int col = nf * 16 + c16;
            float o = (acc2[nf][r] - mu) * rstd * gv[nf] + bvv[nf];
            edges_out[erow + col] = o;
            if constexpr (PRE) {
                float on = __shfl_xor(o, 1, 64);
                if ((c16 & 1) == 0) {
                    __hip_bfloat162 v;
                    v.x = __float2bfloat16(o);
                    v.y = __float2bfloat16(on);
                    unsafeAtomicAdd(&aggB[((size_t)dn * D + col) >> 1], v);
                }
            } else {
                atomicAdd(aggF + (size_t)dn * D + col, o);
            }
        }
    }
}

// ---------------------------------------------------------------------------
// Node kernel: 64 nodes/block; in = [x, agg] (256).
// BF16AGG=true: agg read as bf16 (aggB); else f32 (aggF).
// ---------------------------------------------------------------------------
template<bool BF16AGG>
__global__ __launch_bounds__(BLK, 4) void node_kernel(
    const float* __restrict__ x,
    const float* __restrict__ aggF,
    const __bf16* __restrict__ aggB,
    const __bf16* __restrict__ W1f,
    const float* __restrict__ b1,
    const __bf16* __restrict__ W2f,
    const float* __restrict__ b2,
    const float* __restrict__ lng, const float* __restrict__ lnb,
    float* __restrict__ nodes_out)
{
    __shared__ __bf16 in_t[TN][264];   // 256 used; h1 aliases cols 0..127

    const int tid = threadIdx.x;
    const int r0g = blockIdx.x * TN;

    #pragma unroll
    for (int it = 0; it < 8; ++it) {
        const int idx = tid + it * BLK;
        const int e   = idx >> 5;
        const int c4  = (idx & 31) << 2;
        const int row = r0g + e;
        fx4 v = {0.f, 0.f, 0.f, 0.f};
        if (row < NNODES) v = *(const fx4*)&x[(size_t)row * D + c4];
        bf16x4 h;
        #pragma unroll
        for (int j = 0; j < 4; ++j) h[j] = (__bf16)v[j];
        *(bf16x4*)&in_t[e][c4] = h;
    }
    #pragma unroll
    for (int it = 0; it < 8; ++it) {
        const int idx = tid + it * BLK;
        const int e   = idx >> 5;
        const int c4  = (idx & 31) << 2;
        const int row = r0g + e;
        bf16x4 h = {(__bf16)0.f, (__bf16)0.f, (__bf16)0.f, (__bf16)0.f};
        if (row < NNODES) {
            if constexpr (BF16AGG) {
                h = *(const bf16x4*)&aggB[(size_t)row * D + c4];
            } else {
                fx4 v = *(const fx4*)&aggF[(size_t)row * D + c4];
                #pragma unroll
                for (int j = 0; j < 4; ++j) h[j] = (__bf16)v[j];
            }
        }
        *(bf16x4*)&in_t[e][128 + c4] = h;
    }
    __syncthreads();

    const int lane  = tid & 63;
    const int wid   = tid >> 6;
    const int wrow0 = wid << 4;
    const int c16   = lane & 15;
    const int kq    = lane >> 4;
    const int ks8   = kq << 3;
    const int lo8   = lane << 3;

    f32x4 acc[8];
    #pragma unroll
    for (int nf = 0; nf < 8; ++nf) acc[nf] = (f32x4){0.f, 0.f, 0.f, 0.f};

    #pragma unroll
    for (int ks = 0; ks < 8; ++ks) {
        bf16x8 a = *(const bf16x8*)&in_t[wrow0 + c16][(ks << 5) + ks8];
        const __bf16* wp = W1f + ((size_t)(ks << 3) << 9) + lo8;
        #pragma unroll
        for (int nf = 0; nf < 8; ++nf) {
            bf16x8 b = *(const bf16x8*)(wp + (nf << 9));
            acc[nf] = __builtin_amdgcn_mfma_f32_16x16x32_bf16(a, b, acc[nf], 0, 0, 0);
        }
    }

    #pragma unroll
    for (int nf = 0; nf < 8; ++nf) {
        const float bb = b1[nf * 16 + c16];
        #pragma unroll
        for (int r = 0; r < 4; ++r) {
            float h = silu_f(acc[nf][r] + bb);
            in_t[wrow0 + kq * 4 + r][nf * 16 + c16] = (__bf16)h;
        }
    }

    f32x4 acc2[8];
    #pragma unroll
    for (int nf = 0; nf < 8; ++nf) acc2[nf] = (f32x4){0.f, 0.f, 0.f, 0.f};

    #pragma unroll
    for (int ks = 0; ks < 4; ++ks) {
        bf16x8 a = *(const bf16x8*)&in_t[wrow0 + c16][(ks << 5) + ks8];
        const __bf16* wp = W2f + ((size_t)(ks << 3) << 9) + lo8;
        #pragma unroll
        for (int nf = 0; nf < 8; ++nf) {
            bf16x8 b = *(const bf16x8*)(wp + (nf << 9));
            acc2[nf] = __builtin_amdgcn_mfma_f32_16x16x32_bf16(a, b, acc2[nf], 0, 0, 0);
        }
    }

    float b2v[8], gv[8], bvv[8];
    #pragma unroll
    for (int nf = 0; nf < 8; ++nf) {
        b2v[nf] = b2[nf * 16 + c16];
        gv[nf]  = lng[nf * 16 + c16];
        bvv[nf] = lnb[nf * 16 + c16];
    }

    float s[4] = {0.f, 0.f, 0.f, 0.f}, q[4] = {0.f, 0.f, 0.f, 0.f};
    #pragma unroll
    for (int nf = 0; nf < 8; ++nf)
        #pragma unroll
        for (int r = 0; r < 4; ++r) {
            float zz = acc2[nf][r] + b2v[nf];
            acc2[nf][r] = zz;
            s[r] += zz;
            q[r] += zz * zz;
        }
    #pragma unroll
    for (int m = 1; m <= 8; m <<= 1)
        #pragma unroll
        for (int r = 0; r < 4; ++r) {
            s[r] += __shfl_xor(s[r], m, 64);
            q[r] += __shfl_xor(q[r], m, 64);
        }

    #pragma unroll
    for (int r = 0; r < 4; ++r) {
        const float mu   = s[r] * (1.0f / 128.0f);
        const float var  = q[r] * (1.0f / 128.0f) - mu * mu;
        const float rstd = rsqrtf(var + LN_EPS);
        const int row = r0g + wrow0 + kq * 4 + r;
        if (row >= NNODES) continue;
        const size_t orow = (size_t)row * D;
        #pragma unroll
        for (int nf = 0; nf < 8; ++nf) {
            const int col = nf * 16 + c16;
            float o = (acc2[nf][r] - mu) * rstd * gv[nf] + bvv[nf] + x[orow + col];
            nodes_out[orow + col] = o;
        }
    }
}

extern "C" void kernel_launch(void* const* d_in, const int* in_sizes, int n_in,
                              void* d_out, int out_size, void* d_ws, size_t ws_size,
                              hipStream_t stream) {
    (void)in_sizes; (void)n_in; (void)out_size;

    const float* x         = (const float*)d_in[0];
    const float* edge_attr = (const float*)d_in[1];
    const int*   edge_idx  = (const int*)  d_in[2];
    const float* eW1 = (const float*)d_in[3];
    const float* eb1 = (const float*)d_in[4];
    const float* eW2 = (const float*)d_in[5];
    const float* eb2 = (const float*)d_in[6];
    const float* elg = (const float*)d_in[7];
    const float* elb = (const float*)d_in[8];
    const float* nW1 = (const float*)d_in[9];
    const float* nb1 = (const float*)d_in[10];
    const float* nW2 = (const float*)d_in[11];
    const float* nb2 = (const float*)d_in[12];
    const float* nlg = (const float*)d_in[13];
    const float* nlb = (const float*)d_in[14];

    float* out       = (float*)d_out;
    float* nodes_out = out;
    float* edges_out = out + (size_t)NNODES * D;

    char*   wsb = (char*)d_ws;
    __bf16* ws  = (__bf16*)d_ws;

    prep_weights<<<(WS_ELEMS + 255) / 256, 256, 0, stream>>>(eW1, eW2, nW1, nW2, ws);

    if (ws_size >= WS_NEED) {
        __bf16* aggB = (__bf16*)(wsb + AGGB_OFF);
        __bf16* xB   = (__bf16*)(wsb + XB_OFF);

        prep_x<<<(NNODES * D / 4 + 255) / 256, 256, 0, stream>>>(x, xB);
        hipMemsetAsync(aggB, 0, (size_t)NNODES * D * 2, stream);

        edge_kernel<true><<<NEDGES / TE, BLK, 0, stream>>>(
            x, xB, edge_attr, edge_idx,
            ws + EW1F_OFF, eb1, ws + EW2F_OFF, eb2, elg, elb,
            edges_out, nullptr, (__hip_bfloat162*)aggB);

        node_kernel<true><<<(NNODES + TN - 1) / TN, BLK, 0, stream>>>(
            x, nullptr, aggB,
            ws + NW1F_OFF, nb1, ws + NW2F_OFF, nb2, nlg, nlb,
            nodes_out);
    } else {
        hipMemsetAsync(nodes_out, 0, (size_t)NNODES * D * sizeof(float), stream);

        edge_kernel<false><<<NEDGES / TE, BLK, 0, stream>>>(
            x, nullptr, edge_attr, edge_idx,
            ws + EW1F_OFF, eb1, ws + EW2F_OFF, eb2, elg, elb,
            edges_out, nodes_out, nullptr);

        node_kernel<false><<<(NNODES + TN - 1) / TN, BLK, 0, stream>>>(
            x, nodes_out, nullptr,
            ws + NW1F_OFF, nb1, ws + NW2F_OFF, nb2, nlg, nlb,
            nodes_out);
    }
}